// Round 4
// baseline (1136.429 us; speedup 1.0000x reference)
//
#include <hip/hip_runtime.h>
#include <hip/hip_bf16.h>
#include <hip/hip_fp16.h>

// Problem constants: B=16, C=256, N=2048, NUM_SA=4
static constexpr int Bn = 16;
static constexpr int Cc = 256;
static constexpr int Nn = 2048;
static constexpr int C4 = 64;

typedef _Float16 half_t;
typedef __attribute__((ext_vector_type(8))) _Float16 half8;
typedef __attribute__((ext_vector_type(4))) _Float16 half4;
typedef __attribute__((ext_vector_type(8))) short short8;
typedef __attribute__((ext_vector_type(4))) float float4v;

static constexpr long sNC = (long)Nn * Cc;   // 524288
static constexpr long sNQ = (long)Nn * C4;   // 131072

#define DEVI __device__ __forceinline__

DEVI float bf2f(unsigned short u) { return __uint_as_float(((unsigned)u) << 16); }
DEVI unsigned short f2bf(float f) {
    unsigned x = __float_as_uint(f);
    x += 0x7fffu + ((x >> 16) & 1u);   // RNE
    return (unsigned short)(x >> 16);
}

// async global->LDS, 16B per lane. LDS dest = wave-uniform base + lane*16.
DEVI void gload16(const void* g, void* l) {
    __builtin_amdgcn_global_load_lds(
        (const __attribute__((address_space(1))) unsigned int*)g,
        (__attribute__((address_space(3))) unsigned int*)l, 16, 0, 0);
}

enum { EPI_RAW = 0, EPI_H = 1, EPI_XV = 2, EPI_T = 4 };

// Canonical MFMA GEMM: Y[j][i] = epi( sum_k A[i*K+k] * B[j*K+k] )
template<int MODE, int BM, int BN, int WI, int WJ, bool BF16OUT>
__global__ __launch_bounds__(256)
void mgemm(const half_t* __restrict__ A, long aB,
           const half_t* __restrict__ Bm, long bB,
           void* __restrict__ Yv, long yB, int ldy,
           const half_t* __restrict__ Haux, long hB,
           half_t* __restrict__ hNext, long hnB,
           const float* __restrict__ bias,
           const float* __restrict__ bng, const float* __restrict__ bnb,
           const float* __restrict__ bnm, const float* __restrict__ bnv,
           int K)
{
    __shared__ __align__(16) half_t Als[2][BM][32];
    __shared__ __align__(16) half_t Bls[2][BN][32];

    const int tid  = threadIdx.x;
    const int w    = tid >> 6;
    const int lane = tid & 63;
    const int wi   = (WI == 1) ? 0 : (w & (WI - 1));
    const int wj   = (WI == 1) ? w : (w >> 1);
    const int quad = lane >> 4, m16 = lane & 15;
    const int lr   = lane >> 2, lc = lane & 3;
    const int b    = blockIdx.z;
    const int j0   = blockIdx.x * BN;
    const int i0   = blockIdx.y * BM;

    const half_t* Ab = A + (size_t)b * aB;
    const half_t* Bb = Bm + (size_t)b * bB;

    float4v acc[4][4];
    #pragma unroll
    for (int i = 0; i < 4; ++i)
        #pragma unroll
        for (int j = 0; j < 4; ++j) acc[i][j] = (float4v)0.f;

    for (int k0 = 0; k0 < K; k0 += 64) {
        #pragma unroll
        for (int s = 0; s < 2; ++s) {
            const int kk = k0 + s * 32 + lc * 8;
            #pragma unroll
            for (int t = 0; t < BM / 64; ++t) {
                const int row = (t * 4 + w) * 16;
                gload16(Ab + (size_t)(i0 + row + lr) * K + kk, &Als[s][row][0]);
            }
            #pragma unroll
            for (int t = 0; t < BN / 64; ++t) {
                const int row = (t * 4 + w) * 16;
                gload16(Bb + (size_t)(j0 + row + lr) * K + kk, &Bls[s][row][0]);
            }
        }
        __syncthreads();
        #pragma unroll
        for (int s = 0; s < 2; ++s) {
            half8 af[4], bf[4];
            #pragma unroll
            for (int t = 0; t < 4; ++t)
                af[t] = *(const half8*)&Als[s][wi * 64 + t * 16 + m16][quad * 8];
            #pragma unroll
            for (int t = 0; t < 4; ++t)
                bf[t] = *(const half8*)&Bls[s][wj * 64 + t * 16 + m16][quad * 8];
            #pragma unroll
            for (int ti = 0; ti < 4; ++ti)
                #pragma unroll
                for (int tj = 0; tj < 4; ++tj)
                    acc[ti][tj] = __builtin_amdgcn_mfma_f32_16x16x32_f16(
                        af[ti], bf[tj], acc[ti][tj], 0, 0, 0);
        }
        __syncthreads();
    }

    #pragma unroll
    for (int ti = 0; ti < 4; ++ti) {
        const int il = i0 + wi * 64 + ti * 16 + quad * 4;
        #pragma unroll
        for (int tj = 0; tj < 4; ++tj) {
            const int jl = j0 + wj * 64 + tj * 16 + m16;
            float4v v = acc[ti][tj];
            if (MODE == EPI_RAW) {
                half4 o;
                #pragma unroll
                for (int r = 0; r < 4; ++r) o[r] = (half_t)v[r];
                *(half4*)((half_t*)Yv + (size_t)b * yB + (size_t)jl * ldy + il) = o;
            } else if (MODE == EPI_H) {
                half4 o;
                #pragma unroll
                for (int r = 0; r < 4; ++r) {
                    const float sc = bng[il + r] * rsqrtf(bnv[il + r] + 1e-3f);
                    const float sh = bnb[il + r] - bnm[il + r] * sc;
                    o[r] = (half_t)fmaxf(fmaf(v[r], sc, sh), 0.f);
                }
                *(half4*)((half_t*)Yv + (size_t)b * yB + (size_t)jl * ldy + il) = o;
            } else if (MODE == EPI_XV) {
                const float bj = bias[jl];
                if (BF16OUT) {
                    ushort4 o;
                    o.x = f2bf(v[0] + bj); o.y = f2bf(v[1] + bj);
                    o.z = f2bf(v[2] + bj); o.w = f2bf(v[3] + bj);
                    *(ushort4*)((unsigned short*)Yv + (size_t)b * yB + (size_t)jl * ldy + il) = o;
                } else {
                    half4 o;
                    #pragma unroll
                    for (int r = 0; r < 4; ++r) o[r] = (half_t)(v[r] + bj);
                    *(half4*)((half_t*)Yv + (size_t)b * yB + (size_t)jl * ldy + il) = o;
                }
            } else {   // EPI_T
                const float tb2 = bias[jl];
                const float sc  = bng[jl] * rsqrtf(bnv[jl] + 1e-3f);
                const float sh  = bnb[jl] - bnm[jl] * sc;
                float4v o;
                #pragma unroll
                for (int r = 0; r < 4; ++r) {
                    const float t2  = v[r] + tb2;
                    const float rel = fmaxf(fmaf(t2, sc, sh), 0.f);
                    const float hv  = (float)Haux[(size_t)b * hB + (size_t)(il + r) * Cc + jl];
                    const float ov  = hv + rel;
                    o[r] = ov;
                    if (hNext)
                        hNext[(size_t)b * hnB + (size_t)(il + r) * Cc + jl] = (half_t)ov;
                }
                *(float4v*)((float*)Yv + (size_t)b * yB + (size_t)jl * ldy + il) = o;
            }
        }
    }
}

// Pass 1: E = q q^T tile (i=n rows, j=m cols, K=64), NO E store.
// Per-block per-column (max, sumexp) partials -> Pbuf[b][m][16 iblk][2].
__global__ __launch_bounds__(256)
void estats(const half_t* __restrict__ q, float* __restrict__ Pbuf)
{
    __shared__ __align__(16) half_t sA[128 * 64];
    __shared__ __align__(16) half_t sB[128 * 64];
    __shared__ float red[2][2][4][16][2];   // [wi][wj][tj][m16][{max,sum}]
    const int tid = threadIdx.x, w = tid >> 6, lane = tid & 63;
    const int wi = w & 1, wj = w >> 1, quad = lane >> 4, m16 = lane & 15;
    const int b = blockIdx.z, j0 = blockIdx.x * 128, i0 = blockIdx.y * 128;
    const half_t* qb = q + (size_t)b * sNQ;

    #pragma unroll
    for (int t = 0; t < 4; ++t) {
        const int g = w * 256 + t * 64;
        gload16(qb + (size_t)i0 * 64 + (size_t)(g + lane) * 8, sA + g * 8);
        gload16(qb + (size_t)j0 * 64 + (size_t)(g + lane) * 8, sB + g * 8);
    }
    __syncthreads();

    half8 an[4][2], bm[4][2];
    #pragma unroll
    for (int t = 0; t < 4; ++t)
        #pragma unroll
        for (int ks = 0; ks < 2; ++ks) {
            an[t][ks] = *(const half8*)&sA[(wi * 64 + t * 16 + m16) * 64 + ks * 32 + quad * 8];
            bm[t][ks] = *(const half8*)&sB[(wj * 64 + t * 16 + m16) * 64 + ks * 32 + quad * 8];
        }

    #pragma unroll
    for (int tj = 0; tj < 4; ++tj) {
        float4v e[4];
        #pragma unroll
        for (int ti = 0; ti < 4; ++ti) {
            e[ti] = (float4v)0.f;
            e[ti] = __builtin_amdgcn_mfma_f32_16x16x32_f16(an[ti][0], bm[tj][0], e[ti], 0, 0, 0);
            e[ti] = __builtin_amdgcn_mfma_f32_16x16x32_f16(an[ti][1], bm[tj][1], e[ti], 0, 0, 0);
        }
        float lmax = -1e30f;
        #pragma unroll
        for (int ti = 0; ti < 4; ++ti)
            #pragma unroll
            for (int r = 0; r < 4; ++r) lmax = fmaxf(lmax, e[ti][r]);
        lmax = fmaxf(lmax, __shfl_xor(lmax, 16));
        lmax = fmaxf(lmax, __shfl_xor(lmax, 32));
        float ls = 0.f;
        #pragma unroll
        for (int ti = 0; ti < 4; ++ti)
            #pragma unroll
            for (int r = 0; r < 4; ++r) ls += __expf(e[ti][r] - lmax);
        ls += __shfl_xor(ls, 16);
        ls += __shfl_xor(ls, 32);
        if (quad == 0) { red[wi][wj][tj][m16][0] = lmax; red[wi][wj][tj][m16][1] = ls; }
    }
    __syncthreads();
    if (tid < 128) {
        const int wj2 = tid >> 6, tj2 = (tid >> 4) & 3, mm = tid & 15;
        const float m0 = red[0][wj2][tj2][mm][0], s0 = red[0][wj2][tj2][mm][1];
        const float m1 = red[1][wj2][tj2][mm][0], s1 = red[1][wj2][tj2][mm][1];
        const float M = fmaxf(m0, m1);
        const float S = s0 * __expf(m0 - M) + s1 * __expf(m1 - M);
        const int m = j0 + wj2 * 64 + tj2 * 16 + mm;
        *(float2*)(Pbuf + (((size_t)b * Nn + m) * 16 + blockIdx.y) * 2) = make_float2(M, S);
    }
}

// Merge 16 per-block partials -> mx[b][m], inv[b][m].
__global__ __launch_bounds__(256)
void statsreduce(const float* __restrict__ Pbuf, float* __restrict__ mx, float* __restrict__ inv)
{
    const int id = blockIdx.x * 256 + threadIdx.x;   // 0..32767
    const int b = id >> 11, m = id & 2047;
    const float2* p = (const float2*)(Pbuf + ((size_t)b * Nn + m) * 32);
    float M = -1e30f;
    #pragma unroll
    for (int i = 0; i < 16; ++i) M = fmaxf(M, p[i].x);
    float S = 0.f;
    #pragma unroll
    for (int i = 0; i < 16; ++i) S += p[i].y * __expf(p[i].x - M);
    mx[(size_t)b * Nn + m]  = M;
    inv[(size_t)b * Nn + m] = 1.0f / S;
}

// Pass 2: fused attention-apply.  Per block: c-tile i0 (128), m-tile j0 (128).
// Loop n-chunks of 128: E-tile = q[n] q[m]^T (MFMA, K=64), P = exp(E-mx[n])*inv[n]
// (bf16, via LDS), acc += xv[c][n] @ P[m][n]^T (MFMA, K=128). cs[m] accumulated
// from P in registers.  Epilogue: d[m][c] = h[m][c] - acc/(1e-9+cs[m])  (fp16).
__global__ __launch_bounds__(256, 2)
void flashxr(const half_t* __restrict__ q, const half_t* __restrict__ xv,
             const half_t* __restrict__ h, const float* __restrict__ mx,
             const float* __restrict__ inv, half_t* __restrict__ dS)
{
    __shared__ __align__(16) half_t sQ[128 * 64];     // 16 KB: qA chunk (n rows)
    __shared__ __align__(16) half_t sXV[128 * 128];   // 32 KB: xv tile (c rows, bf16)
    __shared__ __align__(16) half_t sP[128 * 128];    // 32 KB: P tile (m rows, bf16); also qB init + cs buf

    const int tid = threadIdx.x, w = tid >> 6, lane = tid & 63;
    const int wi = w & 1, wj = w >> 1, quad = lane >> 4, m16 = lane & 15;
    const int b = blockIdx.z, j0 = blockIdx.x * 128, i0 = blockIdx.y * 128;
    const half_t* qb  = q + (size_t)b * sNQ;
    const half_t* xvb = xv + (size_t)b * sNC;   // [256][2048] bf16 bits

    // init: stage qB (m rows j0..j0+128) into sP, read B' frags to regs
    #pragma unroll
    for (int t = 0; t < 4; ++t) {
        const int g = w * 256 + t * 64;
        gload16(qb + (size_t)j0 * 64 + (size_t)(g + lane) * 8, sP + g * 8);
    }
    __syncthreads();
    half8 bq[4][2];
    #pragma unroll
    for (int tj = 0; tj < 4; ++tj)
        #pragma unroll
        for (int ks = 0; ks < 2; ++ks)
            bq[tj][ks] = *(const half8*)&sP[(wj * 64 + tj * 16 + m16) * 64 + ks * 32 + quad * 8];
    __syncthreads();   // all reads done before sP is overwritten with P

    float4v acc[4][4];
    #pragma unroll
    for (int i = 0; i < 4; ++i)
        #pragma unroll
        for (int j = 0; j < 4; ++j) acc[i][j] = (float4v)0.f;
    float csa[4] = {0.f, 0.f, 0.f, 0.f};

    const float* mxb = mx + (size_t)b * Nn;
    const float* ivb = inv + (size_t)b * Nn;

    for (int nc = 0; nc < 16; ++nc) {
        // stage qA chunk (n rows) + xv tile (c rows, n-cols chunk)
        #pragma unroll
        for (int t = 0; t < 4; ++t) {
            const int g = w * 256 + t * 64;
            gload16(qb + (size_t)(nc * 128) * 64 + (size_t)(g + lane) * 8, sQ + g * 8);
        }
        #pragma unroll
        for (int t = 0; t < 8; ++t) {
            const int g0 = w * 512 + t * 64;
            const int g  = g0 + lane;
            gload16(xvb + (size_t)(i0 + (g >> 4)) * Nn + nc * 128 + (g & 15) * 8, sXV + g0 * 8);
        }
        __syncthreads();

        // E tile + softmax transform -> sP
        half8 an[4][2];
        #pragma unroll
        for (int ti = 0; ti < 4; ++ti)
            #pragma unroll
            for (int ks = 0; ks < 2; ++ks)
                an[ti][ks] = *(const half8*)&sQ[(wi * 64 + ti * 16 + m16) * 64 + ks * 32 + quad * 8];

        const int nbase = nc * 128 + wi * 64 + quad * 4;
        #pragma unroll
        for (int tj = 0; tj < 4; ++tj) {
            const int mrow = wj * 64 + tj * 16 + m16;
            float4v e[4];
            #pragma unroll
            for (int ti = 0; ti < 4; ++ti) {
                e[ti] = (float4v)0.f;
                e[ti] = __builtin_amdgcn_mfma_f32_16x16x32_f16(an[ti][0], bq[tj][0], e[ti], 0, 0, 0);
                e[ti] = __builtin_amdgcn_mfma_f32_16x16x32_f16(an[ti][1], bq[tj][1], e[ti], 0, 0, 0);
            }
            float cpart = 0.f;
            #pragma unroll
            for (int ti = 0; ti < 4; ++ti) {
                const int ng = nbase + ti * 16;
                const float4v m4 = *(const float4v*)&mxb[ng];
                const float4v i4 = *(const float4v*)&ivb[ng];
                ushort4 pk;
                #pragma unroll
                for (int r = 0; r < 4; ++r) {
                    const float p = __expf(e[ti][r] - m4[r]) * i4[r];
                    cpart += p;
                    (&pk.x)[r] = f2bf(p);
                }
                *(ushort4*)&((unsigned short*)sP)[(size_t)mrow * 128 + wi * 64 + ti * 16 + quad * 4] = pk;
            }
            csa[tj] += cpart;
        }
        __syncthreads();

        // xr accumulate: acc[c][m] += xv[c][k=n] * P[m][k=n], K = 128
        #pragma unroll
        for (int ks = 0; ks < 4; ++ks) {
            short8 xa[4], pb[4];
            #pragma unroll
            for (int ti = 0; ti < 4; ++ti)
                xa[ti] = *(const short8*)&sXV[(wi * 64 + ti * 16 + m16) * 128 + ks * 32 + quad * 8];
            #pragma unroll
            for (int tj = 0; tj < 4; ++tj)
                pb[tj] = *(const short8*)&sP[(wj * 64 + tj * 16 + m16) * 128 + ks * 32 + quad * 8];
            #pragma unroll
            for (int ti = 0; ti < 4; ++ti)
                #pragma unroll
                for (int tj = 0; tj < 4; ++tj)
                    acc[ti][tj] = __builtin_amdgcn_mfma_f32_16x16x32_bf16(
                        xa[ti], pb[tj], acc[ti][tj], 0, 0, 0);
        }
        __syncthreads();   // protect sQ/sXV/sP before next chunk's staging/writes
    }

    // colsum reduce: quad butterfly, then cross-wi via LDS (sP reused as float buf)
    #pragma unroll
    for (int tj = 0; tj < 4; ++tj) {
        csa[tj] += __shfl_xor(csa[tj], 16);
        csa[tj] += __shfl_xor(csa[tj], 32);
    }
    float* fb = (float*)sP;
    if (lane < 16) {
        #pragma unroll
        for (int tj = 0; tj < 4; ++tj)
            fb[wi * 128 + wj * 64 + tj * 16 + lane] = csa[tj];
    }
    __syncthreads();
    float csr[4];
    #pragma unroll
    for (int tj = 0; tj < 4; ++tj) {
        const float c0 = fb[0   + wj * 64 + tj * 16 + m16];
        const float c1 = fb[128 + wj * 64 + tj * 16 + m16];
        csr[tj] = 1.0f / (1e-9f + c0 + c1);
    }

    const half_t* hb = h + (size_t)b * sNC;
    half_t* db = dS + (size_t)b * sNC;
    #pragma unroll
    for (int ti = 0; ti < 4; ++ti) {
        const int cg = i0 + wi * 64 + ti * 16 + quad * 4;
        #pragma unroll
        for (int tj = 0; tj < 4; ++tj) {
            const int mg = j0 + wj * 64 + tj * 16 + m16;
            const half4 hv = *(const half4*)&hb[(size_t)mg * Cc + cg];
            half4 o;
            #pragma unroll
            for (int r = 0; r < 4; ++r)
                o[r] = (half_t)((float)hv[r] - acc[ti][tj][r] * csr[tj]);
            *(half4*)&db[(size_t)mg * Cc + cg] = o;
        }
    }
}

// x [B,C,N] fp32 -> xT [B,N,C] fp16
__global__ __launch_bounds__(256)
void xpose_cast(const float* __restrict__ x, half_t* __restrict__ xT)
{
    __shared__ half_t tile[32][33];
    const int tx = threadIdx.x & 31, ty = threadIdx.x >> 5;
    const int n0 = blockIdx.x * 32, c0 = blockIdx.y * 32, b = blockIdx.z;
    #pragma unroll
    for (int r = 0; r < 4; ++r)
        tile[ty * 4 + r][tx] =
            (half_t)x[((size_t)b * Cc + c0 + ty * 4 + r) * Nn + n0 + tx];
    __syncthreads();
    #pragma unroll
    for (int r = 0; r < 4; ++r)
        xT[((size_t)b * Nn + n0 + ty * 4 + r) * Cc + c0 + tx] = tile[tx][ty * 4 + r];
}

__global__ __launch_bounds__(256)
void castk(const float* __restrict__ s, half_t* __restrict__ d, int n)
{
    const int i = (blockIdx.x * 256 + threadIdx.x) * 4;
    if (i < n) {
        const float4v v = *(const float4v*)(s + i);
        half4 o;
        #pragma unroll
        for (int r = 0; r < 4; ++r) o[r] = (half_t)v[r];
        *(half4*)(d + i) = o;
    }
}

extern "C" void kernel_launch(void* const* d_in, const int* in_sizes, int n_in,
                              void* d_out, int out_size, void* d_ws, size_t ws_size,
                              hipStream_t stream)
{
    const float* x    = (const float*)d_in[0];
    const float* c1w  = (const float*)d_in[1];
    const float* c2w  = (const float*)d_in[2];
    const float* bn1g = (const float*)d_in[3], *bn1b = (const float*)d_in[4];
    const float* bn1m = (const float*)d_in[5], *bn1v = (const float*)d_in[6];
    const float* bn2g = (const float*)d_in[7], *bn2b = (const float*)d_in[8];
    const float* bn2m = (const float*)d_in[9], *bn2v = (const float*)d_in[10];
    const float* qkw  = (const float*)d_in[11];
    const float* vw   = (const float*)d_in[12];
    const float* vb   = (const float*)d_in[13];
    const float* tw   = (const float*)d_in[14];
    const float* tb   = (const float*)d_in[15];
    const float* sag  = (const float*)d_in[16];
    const float* sab  = (const float*)d_in[17];
    const float* sam  = (const float*)d_in[18];
    const float* sav  = (const float*)d_in[19];
    float* out = (float*)d_out;

    // ---- workspace layout ----
    char* ws = (char*)d_ws;
    const size_t HSZ = (size_t)Bn * Nn * Cc * 2;          // 16 MB
    half_t* xT   = (half_t*)(ws);
    half_t* hA   = (half_t*)(ws + HSZ);
    half_t* hBuf = (half_t*)(ws + 2 * HSZ);
    half_t* q_s  = (half_t*)(ws + 3 * HSZ);               // 4 MB
    half_t* xv_s = (half_t*)(ws + 3 * HSZ + (size_t)4194304);       // 16 MB (bf16)
    half_t* d_s  = (half_t*)(ws + 4 * HSZ + (size_t)4194304);       // 16 MB
    float*  mx   = (float*) (ws + 5 * HSZ + (size_t)4194304);       // 128 KB
    float*  inv  = (float*) (ws + 5 * HSZ + (size_t)4325376);       // 128 KB
    float*  Pbuf = (float*) (ws + 5 * HSZ + (size_t)4456448);       // 4 MB
    half_t* wc1  = (half_t*)(ws + 5 * HSZ + (size_t)8650752);
    half_t* wc2  = wc1 + 65536;
    half_t* wqk  = wc2 + 65536;
    half_t* wv   = wqk + 65536;
    half_t* wt   = wv  + 262144;

    dim3 blk(256);

    castk<<<64,  blk, 0, stream>>>(c1w, wc1, 65536);
    castk<<<64,  blk, 0, stream>>>(c2w, wc2, 65536);
    castk<<<64,  blk, 0, stream>>>(qkw, wqk, 65536);
    castk<<<256, blk, 0, stream>>>(vw,  wv,  262144);
    castk<<<256, blk, 0, stream>>>(tw,  wt,  262144);
    xpose_cast<<<dim3(Nn / 32, Cc / 32, Bn), blk, 0, stream>>>(x, xT);

    // conv1 / conv2 -> h[n][c] fp16
    mgemm<EPI_H, 128, 128, 2, 2, false><<<dim3(16, 2, Bn), blk, 0, stream>>>(
        wc1, 0, xT, sNC, hA, sNC, Cc, nullptr, 0, nullptr, 0,
        nullptr, bn1g, bn1b, bn1m, bn1v, Cc);
    mgemm<EPI_H, 128, 128, 2, 2, false><<<dim3(16, 2, Bn), blk, 0, stream>>>(
        wc2, 0, hA, sNC, hBuf, sNC, Cc, nullptr, 0, nullptr, 0,
        nullptr, bn2g, bn2b, bn2m, bn2v, Cc);

    half_t* hcur = hBuf;
    half_t* hnxt = hA;
    for (int L = 0; L < 4; ++L) {
        // q[n][64] fp16
        mgemm<EPI_RAW, 64, 256, 1, 4, false><<<dim3(8, 1, Bn), blk, 0, stream>>>(
            wqk + (long)L * C4 * Cc, 0, hcur, sNC, q_s, sNQ, C4,
            nullptr, 0, nullptr, 0,
            nullptr, nullptr, nullptr, nullptr, nullptr, Cc);
        // softmax stats (no E materialization)
        estats<<<dim3(16, 16, Bn), blk, 0, stream>>>(q_s, Pbuf);
        statsreduce<<<128, blk, 0, stream>>>(Pbuf, mx, inv);
        // xv[c][n] bf16
        mgemm<EPI_XV, 128, 128, 2, 2, true><<<dim3(2, 16, Bn), blk, 0, stream>>>(
            hcur, sNC, wv + (long)L * Cc * Cc, 0, xv_s, (long)Cc * Nn, Nn,
            nullptr, 0, nullptr, 0,
            vb + L * Cc, nullptr, nullptr, nullptr, nullptr, Cc);
        // fused: d[m][c] = h - (xv@attn)/(1e-9+colsum)
        flashxr<<<dim3(16, 2, Bn), blk, 0, stream>>>(
            q_s, xv_s, hcur, mx, inv, d_s);
        // out_L = h + relu(bn(tw @ d + tb)); h_next fp16
        mgemm<EPI_T, 128, 128, 2, 2, false><<<dim3(2, 16, Bn), blk, 0, stream>>>(
            d_s, sNC, wt + (long)L * Cc * Cc, 0,
            out + (long)L * Cc * Nn, (long)4 * Cc * Nn, Nn,
            hcur, sNC, (L < 3) ? hnxt : nullptr, sNC,
            tb + L * Cc, sag + L * Cc, sab + L * Cc, sam + L * Cc, sav + L * Cc,
            Cc);
        half_t* tmp = hcur; hcur = hnxt; hnxt = tmp;
    }
}

// Round 5
// 880.191 us; speedup vs baseline: 1.2911x; 1.2911x over previous
//
#include <hip/hip_runtime.h>
#include <hip/hip_bf16.h>
#include <hip/hip_fp16.h>

// Problem constants: B=16, C=256, N=2048, NUM_SA=4
static constexpr int Bn = 16;
static constexpr int Cc = 256;
static constexpr int Nn = 2048;
static constexpr int C4 = 64;

typedef _Float16 half_t;
typedef __attribute__((ext_vector_type(8))) _Float16 half8;
typedef __attribute__((ext_vector_type(4))) _Float16 half4;
typedef __attribute__((ext_vector_type(8))) short short8;
typedef __attribute__((ext_vector_type(4))) float float4v;

static constexpr long sNC = (long)Nn * Cc;   // 524288
static constexpr long sNQ = (long)Nn * C4;   // 131072

#define DEVI __device__ __forceinline__

DEVI float bf2f(unsigned short u) { return __uint_as_float(((unsigned)u) << 16); }
DEVI unsigned short f2bf(float f) {
    unsigned x = __float_as_uint(f);
    x += 0x7fffu + ((x >> 16) & 1u);   // RNE
    return (unsigned short)(x >> 16);
}

// async global->LDS, 16B per lane. LDS dest = wave-uniform base + lane*16.
DEVI void gload16(const void* g, void* l) {
    __builtin_amdgcn_global_load_lds(
        (const __attribute__((address_space(1))) unsigned int*)g,
        (__attribute__((address_space(3))) unsigned int*)l, 16, 0, 0);
}

enum { EPI_RAW = 0, EPI_H = 1, EPI_XV = 2, EPI_T = 4 };

// Canonical MFMA GEMM: Y[j][i] = epi( sum_k A[i*K+k] * B[j*K+k] )
template<int MODE, int BM, int BN, int WI, int WJ, bool BF16OUT>
__global__ __launch_bounds__(256)
void mgemm(const half_t* __restrict__ A, long aB,
           const half_t* __restrict__ Bm, long bB,
           void* __restrict__ Yv, long yB, int ldy,
           const half_t* __restrict__ Haux, long hB,
           half_t* __restrict__ hNext, long hnB,
           const float* __restrict__ bias,
           const float* __restrict__ bng, const float* __restrict__ bnb,
           const float* __restrict__ bnm, const float* __restrict__ bnv,
           int K)
{
    __shared__ __align__(16) half_t Als[2][BM][32];
    __shared__ __align__(16) half_t Bls[2][BN][32];

    const int tid  = threadIdx.x;
    const int w    = tid >> 6;
    const int lane = tid & 63;
    const int wi   = (WI == 1) ? 0 : (w & (WI - 1));
    const int wj   = (WI == 1) ? w : (w >> 1);
    const int quad = lane >> 4, m16 = lane & 15;
    const int lr   = lane >> 2, lc = lane & 3;
    const int b    = blockIdx.z;
    const int j0   = blockIdx.x * BN;
    const int i0   = blockIdx.y * BM;

    const half_t* Ab = A + (size_t)b * aB;
    const half_t* Bb = Bm + (size_t)b * bB;

    float4v acc[4][4];
    #pragma unroll
    for (int i = 0; i < 4; ++i)
        #pragma unroll
        for (int j = 0; j < 4; ++j) acc[i][j] = (float4v)0.f;

    for (int k0 = 0; k0 < K; k0 += 64) {
        #pragma unroll
        for (int s = 0; s < 2; ++s) {
            const int kk = k0 + s * 32 + lc * 8;
            #pragma unroll
            for (int t = 0; t < BM / 64; ++t) {
                const int row = (t * 4 + w) * 16;
                gload16(Ab + (size_t)(i0 + row + lr) * K + kk, &Als[s][row][0]);
            }
            #pragma unroll
            for (int t = 0; t < BN / 64; ++t) {
                const int row = (t * 4 + w) * 16;
                gload16(Bb + (size_t)(j0 + row + lr) * K + kk, &Bls[s][row][0]);
            }
        }
        __syncthreads();
        #pragma unroll
        for (int s = 0; s < 2; ++s) {
            half8 af[4], bf[4];
            #pragma unroll
            for (int t = 0; t < 4; ++t)
                af[t] = *(const half8*)&Als[s][wi * 64 + t * 16 + m16][quad * 8];
            #pragma unroll
            for (int t = 0; t < 4; ++t)
                bf[t] = *(const half8*)&Bls[s][wj * 64 + t * 16 + m16][quad * 8];
            #pragma unroll
            for (int ti = 0; ti < 4; ++ti)
                #pragma unroll
                for (int tj = 0; tj < 4; ++tj)
                    acc[ti][tj] = __builtin_amdgcn_mfma_f32_16x16x32_f16(
                        af[ti], bf[tj], acc[ti][tj], 0, 0, 0);
        }
        __syncthreads();
    }

    #pragma unroll
    for (int ti = 0; ti < 4; ++ti) {
        const int il = i0 + wi * 64 + ti * 16 + quad * 4;
        #pragma unroll
        for (int tj = 0; tj < 4; ++tj) {
            const int jl = j0 + wj * 64 + tj * 16 + m16;
            float4v v = acc[ti][tj];
            if (MODE == EPI_RAW) {
                half4 o;
                #pragma unroll
                for (int r = 0; r < 4; ++r) o[r] = (half_t)v[r];
                *(half4*)((half_t*)Yv + (size_t)b * yB + (size_t)jl * ldy + il) = o;
            } else if (MODE == EPI_H) {
                half4 o;
                #pragma unroll
                for (int r = 0; r < 4; ++r) {
                    const float sc = bng[il + r] * rsqrtf(bnv[il + r] + 1e-3f);
                    const float sh = bnb[il + r] - bnm[il + r] * sc;
                    o[r] = (half_t)fmaxf(fmaf(v[r], sc, sh), 0.f);
                }
                *(half4*)((half_t*)Yv + (size_t)b * yB + (size_t)jl * ldy + il) = o;
            } else if (MODE == EPI_XV) {
                const float bj = bias[jl];
                if (BF16OUT) {
                    ushort4 o;
                    o.x = f2bf(v[0] + bj); o.y = f2bf(v[1] + bj);
                    o.z = f2bf(v[2] + bj); o.w = f2bf(v[3] + bj);
                    *(ushort4*)((unsigned short*)Yv + (size_t)b * yB + (size_t)jl * ldy + il) = o;
                } else {
                    half4 o;
                    #pragma unroll
                    for (int r = 0; r < 4; ++r) o[r] = (half_t)(v[r] + bj);
                    *(half4*)((half_t*)Yv + (size_t)b * yB + (size_t)jl * ldy + il) = o;
                }
            } else {   // EPI_T
                const float tb2 = bias[jl];
                const float sc  = bng[jl] * rsqrtf(bnv[jl] + 1e-3f);
                const float sh  = bnb[jl] - bnm[jl] * sc;
                float4v o;
                #pragma unroll
                for (int r = 0; r < 4; ++r) {
                    const float t2  = v[r] + tb2;
                    const float rel = fmaxf(fmaf(t2, sc, sh), 0.f);
                    const float hv  = (float)Haux[(size_t)b * hB + (size_t)(il + r) * Cc + jl];
                    const float ov  = hv + rel;
                    o[r] = ov;
                    if (hNext)
                        hNext[(size_t)b * hnB + (size_t)(il + r) * Cc + jl] = (half_t)ov;
                }
                *(float4v*)((float*)Yv + (size_t)b * yB + (size_t)jl * ldy + il) = o;
            }
        }
    }
}

// Pass 1: E = q q^T tile (i=n rows, j=m cols, K=64), NO E store.
// Per-block per-column (max, sumexp) partials -> Pbuf[b][m][16 iblk][2].
// LDS tiles XOR-chunk-swizzled (8 chunks/row): chunk c of row r at c^(r&7).
__global__ __launch_bounds__(256)
void estats(const half_t* __restrict__ q, float* __restrict__ Pbuf)
{
    __shared__ __align__(16) half_t sA[128 * 64];
    __shared__ __align__(16) half_t sB[128 * 64];
    __shared__ float red[2][2][4][16][2];   // [wi][wj][tj][m16][{max,sum}]
    const int tid = threadIdx.x, w = tid >> 6, lane = tid & 63;
    const int wi = w & 1, wj = w >> 1, quad = lane >> 4, m16 = lane & 15;
    const int b = blockIdx.z, j0 = blockIdx.x * 128, i0 = blockIdx.y * 128;
    const half_t* qb = q + (size_t)b * sNQ;

    #pragma unroll
    for (int t = 0; t < 4; ++t) {
        const int g = w * 256 + t * 64 + lane;
        const int r = g >> 3, c = g & 7;
        const int cs = c ^ (r & 7);
        gload16(qb + (size_t)(i0 + r) * 64 + cs * 8, sA + (w * 256 + t * 64) * 8);
        gload16(qb + (size_t)(j0 + r) * 64 + cs * 8, sB + (w * 256 + t * 64) * 8);
    }
    __syncthreads();

    half8 an[4][2], bm[4][2];
    #pragma unroll
    for (int t = 0; t < 4; ++t)
        #pragma unroll
        for (int ks = 0; ks < 2; ++ks) {
            const int pc = ((ks * 4 + quad) ^ (m16 & 7)) * 8;
            an[t][ks] = *(const half8*)&sA[(wi * 64 + t * 16 + m16) * 64 + pc];
            bm[t][ks] = *(const half8*)&sB[(wj * 64 + t * 16 + m16) * 64 + pc];
        }

    #pragma unroll
    for (int tj = 0; tj < 4; ++tj) {
        float4v e[4];
        #pragma unroll
        for (int ti = 0; ti < 4; ++ti) {
            e[ti] = (float4v)0.f;
            e[ti] = __builtin_amdgcn_mfma_f32_16x16x32_f16(an[ti][0], bm[tj][0], e[ti], 0, 0, 0);
            e[ti] = __builtin_amdgcn_mfma_f32_16x16x32_f16(an[ti][1], bm[tj][1], e[ti], 0, 0, 0);
        }
        float lmax = -1e30f;
        #pragma unroll
        for (int ti = 0; ti < 4; ++ti)
            #pragma unroll
            for (int r = 0; r < 4; ++r) lmax = fmaxf(lmax, e[ti][r]);
        lmax = fmaxf(lmax, __shfl_xor(lmax, 16));
        lmax = fmaxf(lmax, __shfl_xor(lmax, 32));
        float ls = 0.f;
        #pragma unroll
        for (int ti = 0; ti < 4; ++ti)
            #pragma unroll
            for (int r = 0; r < 4; ++r) ls += __expf(e[ti][r] - lmax);
        ls += __shfl_xor(ls, 16);
        ls += __shfl_xor(ls, 32);
        if (quad == 0) { red[wi][wj][tj][m16][0] = lmax; red[wi][wj][tj][m16][1] = ls; }
    }
    __syncthreads();
    if (tid < 128) {
        const int wj2 = tid >> 6, tj2 = (tid >> 4) & 3, mm = tid & 15;
        const float m0 = red[0][wj2][tj2][mm][0], s0 = red[0][wj2][tj2][mm][1];
        const float m1 = red[1][wj2][tj2][mm][0], s1 = red[1][wj2][tj2][mm][1];
        const float M = fmaxf(m0, m1);
        const float S = s0 * __expf(m0 - M) + s1 * __expf(m1 - M);
        const int m = j0 + wj2 * 64 + tj2 * 16 + mm;
        *(float2*)(Pbuf + (((size_t)b * Nn + m) * 16 + blockIdx.y) * 2) = make_float2(M, S);
    }
}

// Merge 16 per-block partials -> mx[b][m], inv[b][m].
__global__ __launch_bounds__(256)
void statsreduce(const float* __restrict__ Pbuf, float* __restrict__ mx, float* __restrict__ inv)
{
    const int id = blockIdx.x * 256 + threadIdx.x;   // 0..32767
    const int b = id >> 11, m = id & 2047;
    const float2* p = (const float2*)(Pbuf + ((size_t)b * Nn + m) * 32);
    float M = -1e30f;
    #pragma unroll
    for (int i = 0; i < 16; ++i) M = fmaxf(M, p[i].x);
    float S = 0.f;
    #pragma unroll
    for (int i = 0; i < 16; ++i) S += p[i].y * __expf(p[i].x - M);
    mx[(size_t)b * Nn + m]  = M;
    inv[(size_t)b * Nn + m] = 1.0f / S;
}

// Pass 2: fused attention-apply.  Per block: c-tile i0 (128), m-tile j0 (128).
// All LDS tiles XOR-chunk-swizzled: 16B chunk c of row r lives at c^(r&(nch-1)).
__global__ __launch_bounds__(256, 2)
void flashxr(const half_t* __restrict__ q, const half_t* __restrict__ xv,
             const half_t* __restrict__ h, const float* __restrict__ mx,
             const float* __restrict__ inv, half_t* __restrict__ dS)
{
    __shared__ __align__(16) half_t sQ[128 * 64];     // 16 KB: qA chunk (n rows, 8 ch/row)
    __shared__ __align__(16) half_t sXV[128 * 128];   // 32 KB: xv tile (c rows, 16 ch/row)
    __shared__ __align__(16) half_t sP[128 * 128];    // 32 KB: P tile / qB init / cs buf

    const int tid = threadIdx.x, w = tid >> 6, lane = tid & 63;
    const int wi = w & 1, wj = w >> 1, quad = lane >> 4, m16 = lane & 15;
    const int b = blockIdx.z, j0 = blockIdx.x * 128, i0 = blockIdx.y * 128;
    const half_t* qb  = q + (size_t)b * sNQ;
    const half_t* xvb = xv + (size_t)b * sNC;   // [256][2048] bf16 bits

    // init: stage qB (m rows j0..j0+128) into sP (swizzled), read B frags to regs
    #pragma unroll
    for (int t = 0; t < 4; ++t) {
        const int g = w * 256 + t * 64 + lane;
        const int r = g >> 3, c = g & 7;
        gload16(qb + (size_t)(j0 + r) * 64 + (c ^ (r & 7)) * 8, sP + (w * 256 + t * 64) * 8);
    }
    __syncthreads();
    half8 bq[4][2];
    #pragma unroll
    for (int tj = 0; tj < 4; ++tj)
        #pragma unroll
        for (int ks = 0; ks < 2; ++ks)
            bq[tj][ks] = *(const half8*)&sP[(wj * 64 + tj * 16 + m16) * 64
                                            + (((ks * 4 + quad) ^ (m16 & 7)) * 8)];
    __syncthreads();   // all reads done before sP is overwritten with P

    float4v acc[4][4];
    #pragma unroll
    for (int i = 0; i < 4; ++i)
        #pragma unroll
        for (int j = 0; j < 4; ++j) acc[i][j] = (float4v)0.f;
    float csa[4] = {0.f, 0.f, 0.f, 0.f};

    const float* mxb = mx + (size_t)b * Nn;
    const float* ivb = inv + (size_t)b * Nn;

    for (int nc = 0; nc < 16; ++nc) {
        // stage qA chunk (n rows, swizzled) + xv tile (c rows, n-chunk, swizzled)
        #pragma unroll
        for (int t = 0; t < 4; ++t) {
            const int g = w * 256 + t * 64 + lane;
            const int r = g >> 3, c = g & 7;
            gload16(qb + (size_t)(nc * 128 + r) * 64 + (c ^ (r & 7)) * 8,
                    sQ + (w * 256 + t * 64) * 8);
        }
        #pragma unroll
        for (int t = 0; t < 8; ++t) {
            const int g = w * 512 + t * 64 + lane;
            const int r = g >> 4, c = g & 15;
            gload16(xvb + (size_t)(i0 + r) * Nn + nc * 128 + (c ^ (r & 15)) * 8,
                    sXV + (w * 512 + t * 64) * 8);
        }
        __syncthreads();

        half8 an[4][2];
        #pragma unroll
        for (int ti = 0; ti < 4; ++ti)
            #pragma unroll
            for (int ks = 0; ks < 2; ++ks)
                an[ti][ks] = *(const half8*)&sQ[(wi * 64 + ti * 16 + m16) * 64
                                                + (((ks * 4 + quad) ^ (m16 & 7)) * 8)];

        // hoisted per-n softmax stats (shared across tj)
        const int nbase = nc * 128 + wi * 64 + quad * 4;
        float4v m4[4], i4[4];
        #pragma unroll
        for (int ti = 0; ti < 4; ++ti) {
            m4[ti] = *(const float4v*)&mxb[nbase + ti * 16];
            i4[ti] = *(const float4v*)&ivb[nbase + ti * 16];
        }

        #pragma unroll
        for (int tj = 0; tj < 4; ++tj) {
            const int mrow = wj * 64 + tj * 16 + m16;
            float4v e[4];
            #pragma unroll
            for (int ti = 0; ti < 4; ++ti) {
                e[ti] = (float4v)0.f;
                e[ti] = __builtin_amdgcn_mfma_f32_16x16x32_f16(an[ti][0], bq[tj][0], e[ti], 0, 0, 0);
                e[ti] = __builtin_amdgcn_mfma_f32_16x16x32_f16(an[ti][1], bq[tj][1], e[ti], 0, 0, 0);
            }
            float cpart = 0.f;
            #pragma unroll
            for (int ti = 0; ti < 4; ++ti) {
                ushort4 pk;
                #pragma unroll
                for (int r = 0; r < 4; ++r) {
                    const float p = __expf(e[ti][r] - m4[ti][r]) * i4[ti][r];
                    cpart += p;
                    (&pk.x)[r] = f2bf(p);
                }
                // logical 16B chunk c = wi*8+ti*2+(quad>>1); sub-chunk (quad&1)*4 halfs
                const int pc = ((wi * 8 + ti * 2 + (quad >> 1)) ^ m16) * 8 + (quad & 1) * 4;
                *(ushort4*)&((unsigned short*)sP)[(size_t)mrow * 128 + pc] = pk;
            }
            csa[tj] += cpart;
        }
        __syncthreads();

        // xr accumulate: acc[c][m] += xv[c][k=n] * P[m][k=n], K = 128
        #pragma unroll
        for (int ks = 0; ks < 4; ++ks) {
            short8 xa[4], pb[4];
            #pragma unroll
            for (int ti = 0; ti < 4; ++ti)
                xa[ti] = *(const short8*)&sXV[(wi * 64 + ti * 16 + m16) * 128
                                              + (((ks * 4 + quad) ^ m16) * 8)];
            #pragma unroll
            for (int tj = 0; tj < 4; ++tj)
                pb[tj] = *(const short8*)&sP[(wj * 64 + tj * 16 + m16) * 128
                                             + (((ks * 4 + quad) ^ m16) * 8)];
            #pragma unroll
            for (int ti = 0; ti < 4; ++ti)
                #pragma unroll
                for (int tj = 0; tj < 4; ++tj)
                    acc[ti][tj] = __builtin_amdgcn_mfma_f32_16x16x32_bf16(
                        xa[ti], pb[tj], acc[ti][tj], 0, 0, 0);
        }
        __syncthreads();   // protect sQ/sXV/sP before next chunk
    }

    // colsum reduce: quad butterfly, then cross-wi via LDS (sP reused as float buf)
    #pragma unroll
    for (int tj = 0; tj < 4; ++tj) {
        csa[tj] += __shfl_xor(csa[tj], 16);
        csa[tj] += __shfl_xor(csa[tj], 32);
    }
    float* fb = (float*)sP;
    if (lane < 16) {
        #pragma unroll
        for (int tj = 0; tj < 4; ++tj)
            fb[wi * 128 + wj * 64 + tj * 16 + lane] = csa[tj];
    }
    __syncthreads();
    float csr[4];
    #pragma unroll
    for (int tj = 0; tj < 4; ++tj) {
        const float c0 = fb[0   + wj * 64 + tj * 16 + m16];
        const float c1 = fb[128 + wj * 64 + tj * 16 + m16];
        csr[tj] = 1.0f / (1e-9f + c0 + c1);
    }

    const half_t* hb = h + (size_t)b * sNC;
    half_t* db = dS + (size_t)b * sNC;
    #pragma unroll
    for (int ti = 0; ti < 4; ++ti) {
        const int cg = i0 + wi * 64 + ti * 16 + quad * 4;
        #pragma unroll
        for (int tj = 0; tj < 4; ++tj) {
            const int mg = j0 + wj * 64 + tj * 16 + m16;
            const half4 hv = *(const half4*)&hb[(size_t)mg * Cc + cg];
            half4 o;
            #pragma unroll
            for (int r = 0; r < 4; ++r)
                o[r] = (half_t)((float)hv[r] - acc[ti][tj][r] * csr[tj]);
            *(half4*)&db[(size_t)mg * Cc + cg] = o;
        }
    }
}

// x [B,C,N] fp32 -> xT [B,N,C] fp16
__global__ __launch_bounds__(256)
void xpose_cast(const float* __restrict__ x, half_t* __restrict__ xT)
{
    __shared__ half_t tile[32][33];
    const int tx = threadIdx.x & 31, ty = threadIdx.x >> 5;
    const int n0 = blockIdx.x * 32, c0 = blockIdx.y * 32, b = blockIdx.z;
    #pragma unroll
    for (int r = 0; r < 4; ++r)
        tile[ty * 4 + r][tx] =
            (half_t)x[((size_t)b * Cc + c0 + ty * 4 + r) * Nn + n0 + tx];
    __syncthreads();
    #pragma unroll
    for (int r = 0; r < 4; ++r)
        xT[((size_t)b * Nn + n0 + ty * 4 + r) * Cc + c0 + tx] = tile[tx][ty * 4 + r];
}

__global__ __launch_bounds__(256)
void castk(const float* __restrict__ s, half_t* __restrict__ d, int n)
{
    const int i = (blockIdx.x * 256 + threadIdx.x) * 4;
    if (i < n) {
        const float4v v = *(const float4v*)(s + i);
        half4 o;
        #pragma unroll
        for (int r = 0; r < 4; ++r) o[r] = (half_t)v[r];
        *(half4*)(d + i) = o;
    }
}

extern "C" void kernel_launch(void* const* d_in, const int* in_sizes, int n_in,
                              void* d_out, int out_size, void* d_ws, size_t ws_size,
                              hipStream_t stream)
{
    const float* x    = (const float*)d_in[0];
    const float* c1w  = (const float*)d_in[1];
    const float* c2w  = (const float*)d_in[2];
    const float* bn1g = (const float*)d_in[3], *bn1b = (const float*)d_in[4];
    const float* bn1m = (const float*)d_in[5], *bn1v = (const float*)d_in[6];
    const float* bn2g = (const float*)d_in[7], *bn2b = (const float*)d_in[8];
    const float* bn2m = (const float*)d_in[9], *bn2v = (const float*)d_in[10];
    const float* qkw  = (const float*)d_in[11];
    const float* vw   = (const float*)d_in[12];
    const float* vb   = (const float*)d_in[13];
    const float* tw   = (const float*)d_in[14];
    const float* tb   = (const float*)d_in[15];
    const float* sag  = (const float*)d_in[16];
    const float* sab  = (const float*)d_in[17];
    const float* sam  = (const float*)d_in[18];
    const float* sav  = (const float*)d_in[19];
    float* out = (float*)d_out;

    // ---- workspace layout ----
    char* ws = (char*)d_ws;
    const size_t HSZ = (size_t)Bn * Nn * Cc * 2;          // 16 MB
    half_t* xT   = (half_t*)(ws);
    half_t* hA   = (half_t*)(ws + HSZ);
    half_t* hBuf = (half_t*)(ws + 2 * HSZ);
    half_t* q_s  = (half_t*)(ws + 3 * HSZ);               // 4 MB
    half_t* xv_s = (half_t*)(ws + 3 * HSZ + (size_t)4194304);       // 16 MB (bf16)
    half_t* d_s  = (half_t*)(ws + 4 * HSZ + (size_t)4194304);       // 16 MB
    float*  mx   = (float*) (ws + 5 * HSZ + (size_t)4194304);       // 128 KB
    float*  inv  = (float*) (ws + 5 * HSZ + (size_t)4325376);       // 128 KB
    float*  Pbuf = (float*) (ws + 5 * HSZ + (size_t)4456448);       // 4 MB
    half_t* wc1  = (half_t*)(ws + 5 * HSZ + (size_t)8650752);
    half_t* wc2  = wc1 + 65536;
    half_t* wqk  = wc2 + 65536;
    half_t* wv   = wqk + 65536;
    half_t* wt   = wv  + 262144;

    dim3 blk(256);

    castk<<<64,  blk, 0, stream>>>(c1w, wc1, 65536);
    castk<<<64,  blk, 0, stream>>>(c2w, wc2, 65536);
    castk<<<64,  blk, 0, stream>>>(qkw, wqk, 65536);
    castk<<<256, blk, 0, stream>>>(vw,  wv,  262144);
    castk<<<256, blk, 0, stream>>>(tw,  wt,  262144);
    xpose_cast<<<dim3(Nn / 32, Cc / 32, Bn), blk, 0, stream>>>(x, xT);

    // conv1 / conv2 -> h[n][c] fp16
    mgemm<EPI_H, 128, 128, 2, 2, false><<<dim3(16, 2, Bn), blk, 0, stream>>>(
        wc1, 0, xT, sNC, hA, sNC, Cc, nullptr, 0, nullptr, 0,
        nullptr, bn1g, bn1b, bn1m, bn1v, Cc);
    mgemm<EPI_H, 128, 128, 2, 2, false><<<dim3(16, 2, Bn), blk, 0, stream>>>(
        wc2, 0, hA, sNC, hBuf, sNC, Cc, nullptr, 0, nullptr, 0,
        nullptr, bn2g, bn2b, bn2m, bn2v, Cc);

    half_t* hcur = hBuf;
    half_t* hnxt = hA;
    for (int L = 0; L < 4; ++L) {
        // q[n][64] fp16
        mgemm<EPI_RAW, 64, 256, 1, 4, false><<<dim3(8, 1, Bn), blk, 0, stream>>>(
            wqk + (long)L * C4 * Cc, 0, hcur, sNC, q_s, sNQ, C4,
            nullptr, 0, nullptr, 0,
            nullptr, nullptr, nullptr, nullptr, nullptr, Cc);
        // softmax stats (no E materialization)
        estats<<<dim3(16, 16, Bn), blk, 0, stream>>>(q_s, Pbuf);
        statsreduce<<<128, blk, 0, stream>>>(Pbuf, mx, inv);
        // xv[c][n] bf16
        mgemm<EPI_XV, 128, 128, 2, 2, true><<<dim3(2, 16, Bn), blk, 0, stream>>>(
            hcur, sNC, wv + (long)L * Cc * Cc, 0, xv_s, (long)Cc * Nn, Nn,
            nullptr, 0, nullptr, 0,
            vb + L * Cc, nullptr, nullptr, nullptr, nullptr, Cc);
        // fused: d[m][c] = h - (xv@attn)/(1e-9+colsum)
        flashxr<<<dim3(16, 2, Bn), blk, 0, stream>>>(
            q_s, xv_s, hcur, mx, inv, d_s);
        // out_L = h + relu(bn(tw @ d + tb)); h_next fp16
        mgemm<EPI_T, 128, 128, 2, 2, false><<<dim3(2, 16, Bn), blk, 0, stream>>>(
            d_s, sNC, wt + (long)L * Cc * Cc, 0,
            out + (long)L * Cc * Nn, (long)4 * Cc * Nn, Nn,
            hcur, sNC, (L < 3) ? hnxt : nullptr, sNC,
            tb + L * Cc, sag + L * Cc, sab + L * Cc, sam + L * Cc, sav + L * Cc,
            Cc);
        half_t* tmp = hcur; hcur = hnxt; hnxt = tmp;
    }
}

// Round 6
// 810.766 us; speedup vs baseline: 1.4017x; 1.0856x over previous
//
#include <hip/hip_runtime.h>
#include <hip/hip_bf16.h>
#include <hip/hip_fp16.h>

// Problem constants: B=16, C=256, N=2048, NUM_SA=4
static constexpr int Bn = 16;
static constexpr int Cc = 256;
static constexpr int Nn = 2048;
static constexpr int C4 = 64;
static constexpr float LOG2E = 1.4426950408889634f;

typedef _Float16 half_t;
typedef __attribute__((ext_vector_type(8))) _Float16 half8;
typedef __attribute__((ext_vector_type(4))) _Float16 half4;
typedef __attribute__((ext_vector_type(8))) short short8;
typedef __attribute__((ext_vector_type(4))) float float4v;

static constexpr long sNC = (long)Nn * Cc;   // 524288
static constexpr long sNQ = (long)Nn * C4;   // 131072

#define DEVI __device__ __forceinline__

DEVI float bf2f(unsigned short u) { return __uint_as_float(((unsigned)u) << 16); }
DEVI unsigned short f2bf(float f) {
    unsigned x = __float_as_uint(f);
    x += 0x7fffu + ((x >> 16) & 1u);   // RNE
    return (unsigned short)(x >> 16);
}

// async global->LDS, 16B per lane. LDS dest = wave-uniform base + lane*16.
DEVI void gload16(const void* g, void* l) {
    __builtin_amdgcn_global_load_lds(
        (const __attribute__((address_space(1))) unsigned int*)g,
        (__attribute__((address_space(3))) unsigned int*)l, 16, 0, 0);
}

enum { EPI_RAW = 0, EPI_H = 1, EPI_XV = 2, EPI_T = 4 };

// Canonical MFMA GEMM: Y[j][i] = epi( sum_k A[i*K+k] * B[j*K+k] )
template<int MODE, int BM, int BN, int WI, int WJ, bool BF16OUT>
__global__ __launch_bounds__(256)
void mgemm(const half_t* __restrict__ A, long aB,
           const half_t* __restrict__ Bm, long bB,
           void* __restrict__ Yv, long yB, int ldy,
           const half_t* __restrict__ Haux, long hB,
           half_t* __restrict__ hNext, long hnB,
           const float* __restrict__ bias,
           const float* __restrict__ bng, const float* __restrict__ bnb,
           const float* __restrict__ bnm, const float* __restrict__ bnv,
           int K)
{
    __shared__ __align__(16) half_t Als[2][BM][32];
    __shared__ __align__(16) half_t Bls[2][BN][32];

    const int tid  = threadIdx.x;
    const int w    = tid >> 6;
    const int lane = tid & 63;
    const int wi   = (WI == 1) ? 0 : (w & (WI - 1));
    const int wj   = (WI == 1) ? w : (w >> 1);
    const int quad = lane >> 4, m16 = lane & 15;
    const int lr   = lane >> 2, lc = lane & 3;
    const int b    = blockIdx.z;
    const int j0   = blockIdx.x * BN;
    const int i0   = blockIdx.y * BM;

    const half_t* Ab = A + (size_t)b * aB;
    const half_t* Bb = Bm + (size_t)b * bB;

    float4v acc[4][4];
    #pragma unroll
    for (int i = 0; i < 4; ++i)
        #pragma unroll
        for (int j = 0; j < 4; ++j) acc[i][j] = (float4v)0.f;

    for (int k0 = 0; k0 < K; k0 += 64) {
        #pragma unroll
        for (int s = 0; s < 2; ++s) {
            const int kk = k0 + s * 32 + lc * 8;
            #pragma unroll
            for (int t = 0; t < BM / 64; ++t) {
                const int row = (t * 4 + w) * 16;
                gload16(Ab + (size_t)(i0 + row + lr) * K + kk, &Als[s][row][0]);
            }
            #pragma unroll
            for (int t = 0; t < BN / 64; ++t) {
                const int row = (t * 4 + w) * 16;
                gload16(Bb + (size_t)(j0 + row + lr) * K + kk, &Bls[s][row][0]);
            }
        }
        __syncthreads();
        #pragma unroll
        for (int s = 0; s < 2; ++s) {
            half8 af[4], bf[4];
            #pragma unroll
            for (int t = 0; t < 4; ++t)
                af[t] = *(const half8*)&Als[s][wi * 64 + t * 16 + m16][quad * 8];
            #pragma unroll
            for (int t = 0; t < 4; ++t)
                bf[t] = *(const half8*)&Bls[s][wj * 64 + t * 16 + m16][quad * 8];
            #pragma unroll
            for (int ti = 0; ti < 4; ++ti)
                #pragma unroll
                for (int tj = 0; tj < 4; ++tj)
                    acc[ti][tj] = __builtin_amdgcn_mfma_f32_16x16x32_f16(
                        af[ti], bf[tj], acc[ti][tj], 0, 0, 0);
        }
        __syncthreads();
    }

    #pragma unroll
    for (int ti = 0; ti < 4; ++ti) {
        const int il = i0 + wi * 64 + ti * 16 + quad * 4;
        #pragma unroll
        for (int tj = 0; tj < 4; ++tj) {
            const int jl = j0 + wj * 64 + tj * 16 + m16;
            float4v v = acc[ti][tj];
            if (MODE == EPI_RAW) {
                half4 o;
                #pragma unroll
                for (int r = 0; r < 4; ++r) o[r] = (half_t)v[r];
                *(half4*)((half_t*)Yv + (size_t)b * yB + (size_t)jl * ldy + il) = o;
            } else if (MODE == EPI_H) {
                half4 o;
                #pragma unroll
                for (int r = 0; r < 4; ++r) {
                    const float sc = bng[il + r] * rsqrtf(bnv[il + r] + 1e-3f);
                    const float sh = bnb[il + r] - bnm[il + r] * sc;
                    o[r] = (half_t)fmaxf(fmaf(v[r], sc, sh), 0.f);
                }
                *(half4*)((half_t*)Yv + (size_t)b * yB + (size_t)jl * ldy + il) = o;
            } else if (MODE == EPI_XV) {
                const float bj = bias[jl];
                if (BF16OUT) {
                    ushort4 o;
                    o.x = f2bf(v[0] + bj); o.y = f2bf(v[1] + bj);
                    o.z = f2bf(v[2] + bj); o.w = f2bf(v[3] + bj);
                    *(ushort4*)((unsigned short*)Yv + (size_t)b * yB + (size_t)jl * ldy + il) = o;
                } else {
                    half4 o;
                    #pragma unroll
                    for (int r = 0; r < 4; ++r) o[r] = (half_t)(v[r] + bj);
                    *(half4*)((half_t*)Yv + (size_t)b * yB + (size_t)jl * ldy + il) = o;
                }
            } else {   // EPI_T
                const float tb2 = bias[jl];
                const float sc  = bng[jl] * rsqrtf(bnv[jl] + 1e-3f);
                const float sh  = bnb[jl] - bnm[jl] * sc;
                float4v o;
                #pragma unroll
                for (int r = 0; r < 4; ++r) {
                    const float t2  = v[r] + tb2;
                    const float rel = fmaxf(fmaf(t2, sc, sh), 0.f);
                    const float hv  = (float)Haux[(size_t)b * hB + (size_t)(il + r) * Cc + jl];
                    const float ov  = hv + rel;
                    o[r] = ov;
                    if (hNext)
                        hNext[(size_t)b * hnB + (size_t)(il + r) * Cc + jl] = (half_t)ov;
                }
                *(float4v*)((float*)Yv + (size_t)b * yB + (size_t)jl * ldy + il) = o;
            }
        }
    }
}

// Pass 1: E = q q^T tile (i=n rows, j=m cols, K=64), NO E store.
// Per-block per-column (max, sumexp) partials -> Pbuf[b][m][16 iblk][2].
__global__ __launch_bounds__(256)
void estats(const half_t* __restrict__ q, float* __restrict__ Pbuf)
{
    __shared__ __align__(16) half_t sA[128 * 64];
    __shared__ __align__(16) half_t sB[128 * 64];
    __shared__ float red[2][2][4][16][2];
    const int tid = threadIdx.x, w = tid >> 6, lane = tid & 63;
    const int wi = w & 1, wj = w >> 1, quad = lane >> 4, m16 = lane & 15;
    const int b = blockIdx.z, j0 = blockIdx.x * 128, i0 = blockIdx.y * 128;
    const half_t* qb = q + (size_t)b * sNQ;

    #pragma unroll
    for (int t = 0; t < 4; ++t) {
        const int g = w * 256 + t * 64 + lane;
        const int r = g >> 3, c = g & 7;
        const int cs = c ^ (r & 7);
        gload16(qb + (size_t)(i0 + r) * 64 + cs * 8, sA + (w * 256 + t * 64) * 8);
        gload16(qb + (size_t)(j0 + r) * 64 + cs * 8, sB + (w * 256 + t * 64) * 8);
    }
    __syncthreads();

    half8 an[4][2], bm[4][2];
    #pragma unroll
    for (int t = 0; t < 4; ++t)
        #pragma unroll
        for (int ks = 0; ks < 2; ++ks) {
            const int pc = ((ks * 4 + quad) ^ (m16 & 7)) * 8;
            an[t][ks] = *(const half8*)&sA[(wi * 64 + t * 16 + m16) * 64 + pc];
            bm[t][ks] = *(const half8*)&sB[(wj * 64 + t * 16 + m16) * 64 + pc];
        }

    #pragma unroll
    for (int tj = 0; tj < 4; ++tj) {
        float4v e[4];
        #pragma unroll
        for (int ti = 0; ti < 4; ++ti) {
            e[ti] = (float4v)0.f;
            e[ti] = __builtin_amdgcn_mfma_f32_16x16x32_f16(an[ti][0], bm[tj][0], e[ti], 0, 0, 0);
            e[ti] = __builtin_amdgcn_mfma_f32_16x16x32_f16(an[ti][1], bm[tj][1], e[ti], 0, 0, 0);
        }
        float lmax = -1e30f;
        #pragma unroll
        for (int ti = 0; ti < 4; ++ti)
            #pragma unroll
            for (int r = 0; r < 4; ++r) lmax = fmaxf(lmax, e[ti][r]);
        lmax = fmaxf(lmax, __shfl_xor(lmax, 16));
        lmax = fmaxf(lmax, __shfl_xor(lmax, 32));
        float ls = 0.f;
        #pragma unroll
        for (int ti = 0; ti < 4; ++ti)
            #pragma unroll
            for (int r = 0; r < 4; ++r) ls += __expf(e[ti][r] - lmax);
        ls += __shfl_xor(ls, 16);
        ls += __shfl_xor(ls, 32);
        if (quad == 0) { red[wi][wj][tj][m16][0] = lmax; red[wi][wj][tj][m16][1] = ls; }
    }
    __syncthreads();
    if (tid < 128) {
        const int wj2 = tid >> 6, tj2 = (tid >> 4) & 3, mm = tid & 15;
        const float m0 = red[0][wj2][tj2][mm][0], s0 = red[0][wj2][tj2][mm][1];
        const float m1 = red[1][wj2][tj2][mm][0], s1 = red[1][wj2][tj2][mm][1];
        const float M = fmaxf(m0, m1);
        const float S = s0 * __expf(m0 - M) + s1 * __expf(m1 - M);
        const int m = j0 + wj2 * 64 + tj2 * 16 + mm;
        *(float2*)(Pbuf + (((size_t)b * Nn + m) * 16 + blockIdx.y) * 2) = make_float2(M, S);
    }
}

// Merge 16 per-block partials -> off[b][m] = log2( exp(mx)*S ) = mx*log2e + log2(S)
// so that attn = exp2( e*log2e - off ).
__global__ __launch_bounds__(256)
void statsreduce(const float* __restrict__ Pbuf, float* __restrict__ off)
{
    const int id = blockIdx.x * 256 + threadIdx.x;   // 0..32767
    const int b = id >> 11, m = id & 2047;
    const float2* p = (const float2*)(Pbuf + ((size_t)b * Nn + m) * 32);
    float M = -1e30f;
    #pragma unroll
    for (int i = 0; i < 16; ++i) M = fmaxf(M, p[i].x);
    float S = 0.f;
    #pragma unroll
    for (int i = 0; i < 16; ++i) S += p[i].y * __expf(p[i].x - M);
    off[(size_t)b * Nn + m] = fmaf(M, LOG2E, __log2f(S));
}

// Pass 2: fused attention-apply. 512 threads (8 waves: 2 wi x 4 wj), wave tile 64x32.
// All LDS tiles XOR-chunk-swizzled: 16B chunk c of row r lives at c^(r&(nch-1)).
__global__ __launch_bounds__(512, 4)
void flashxr(const half_t* __restrict__ q, const half_t* __restrict__ xv,
             const half_t* __restrict__ h, const float* __restrict__ off,
             half_t* __restrict__ dS)
{
    __shared__ __align__(16) half_t sQ[128 * 64];     // 16 KB: qA chunk (n rows, 8 ch/row)
    __shared__ __align__(16) half_t sXV[128 * 128];   // 32 KB: xv tile (c rows, 16 ch/row)
    __shared__ __align__(16) half_t sP[128 * 128];    // 32 KB: P tile / qB init / cs buf

    const int tid = threadIdx.x, w = tid >> 6, lane = tid & 63;
    const int wi = w & 1, wj = w >> 1, quad = lane >> 4, m16 = lane & 15;
    const int b = blockIdx.z, j0 = blockIdx.x * 128, i0 = blockIdx.y * 128;
    const half_t* qb  = q + (size_t)b * sNQ;
    const half_t* xvb = xv + (size_t)b * sNC;   // [256][2048] bf16 bits

    // init: stage qB (m rows j0..j0+128) into sP (swizzled), read B frags to regs
    #pragma unroll
    for (int t = 0; t < 2; ++t) {
        const int g = w * 128 + t * 64 + lane;
        const int r = g >> 3, c = g & 7;
        gload16(qb + (size_t)(j0 + r) * 64 + (c ^ (r & 7)) * 8, sP + (w * 128 + t * 64) * 8);
    }
    __syncthreads();
    half8 bq[2][2];
    #pragma unroll
    for (int tj = 0; tj < 2; ++tj)
        #pragma unroll
        for (int ks = 0; ks < 2; ++ks)
            bq[tj][ks] = *(const half8*)&sP[(wj * 32 + tj * 16 + m16) * 64
                                            + (((ks * 4 + quad) ^ (m16 & 7)) * 8)];
    __syncthreads();   // all reads done before sP is overwritten with P

    float4v acc[4][2];
    #pragma unroll
    for (int i = 0; i < 4; ++i)
        #pragma unroll
        for (int j = 0; j < 2; ++j) acc[i][j] = (float4v)0.f;
    float csa[2] = {0.f, 0.f};

    const float* offb = off + (size_t)b * Nn;

    for (int nc = 0; nc < 16; ++nc) {
        // stage qA chunk (n rows, swizzled) + xv tile (c rows, n-chunk, swizzled)
        #pragma unroll
        for (int t = 0; t < 2; ++t) {
            const int g = w * 128 + t * 64 + lane;
            const int r = g >> 3, c = g & 7;
            gload16(qb + (size_t)(nc * 128 + r) * 64 + (c ^ (r & 7)) * 8,
                    sQ + (w * 128 + t * 64) * 8);
        }
        #pragma unroll
        for (int t = 0; t < 4; ++t) {
            const int g = w * 256 + t * 64 + lane;
            const int r = g >> 4, c = g & 15;
            gload16(xvb + (size_t)(i0 + r) * Nn + nc * 128 + (c ^ (r & 15)) * 8,
                    sXV + (w * 256 + t * 64) * 8);
        }
        __syncthreads();

        // E phase: per ti load an pair, two tj MFMAs, transform, write P
        const int nbase = nc * 128 + wi * 64 + quad * 4;
        #pragma unroll
        for (int ti = 0; ti < 4; ++ti) {
            const int arow = (wi * 64 + ti * 16 + m16) * 64;
            const half8 an0 = *(const half8*)&sQ[arow + ((quad ^ (m16 & 7)) * 8)];
            const half8 an1 = *(const half8*)&sQ[arow + (((4 + quad) ^ (m16 & 7)) * 8)];
            float4v e0 = (float4v)0.f, e1 = (float4v)0.f;
            e0 = __builtin_amdgcn_mfma_f32_16x16x32_f16(an0, bq[0][0], e0, 0, 0, 0);
            e1 = __builtin_amdgcn_mfma_f32_16x16x32_f16(an0, bq[1][0], e1, 0, 0, 0);
            e0 = __builtin_amdgcn_mfma_f32_16x16x32_f16(an1, bq[0][1], e0, 0, 0, 0);
            e1 = __builtin_amdgcn_mfma_f32_16x16x32_f16(an1, bq[1][1], e1, 0, 0, 0);
            const float4v o4 = *(const float4v*)&offb[nbase + ti * 16];
            const int pc = wi * 8 + ti * 2 + (quad >> 1);     // logical 16B chunk
            const int sub = (quad & 1) * 4;
            {
                float c0 = 0.f; ushort4 pk;
                #pragma unroll
                for (int r = 0; r < 4; ++r) {
                    const float p = __builtin_amdgcn_exp2f(fmaf(e0[r], LOG2E, -o4[r]));
                    c0 += p; (&pk.x)[r] = f2bf(p);
                }
                csa[0] += c0;
                const int mrow = wj * 32 + m16;
                *(ushort4*)&((unsigned short*)sP)[(size_t)mrow * 128 + (pc ^ m16) * 8 + sub] = pk;
            }
            {
                float c1 = 0.f; ushort4 pk;
                #pragma unroll
                for (int r = 0; r < 4; ++r) {
                    const float p = __builtin_amdgcn_exp2f(fmaf(e1[r], LOG2E, -o4[r]));
                    c1 += p; (&pk.x)[r] = f2bf(p);
                }
                csa[1] += c1;
                const int mrow = wj * 32 + 16 + m16;
                *(ushort4*)&((unsigned short*)sP)[(size_t)mrow * 128 + (pc ^ m16) * 8 + sub] = pk;
            }
        }
        __syncthreads();

        // XR phase: acc[c][m] += xv[c][k=n] * P[m][k=n], K = 128
        #pragma unroll
        for (int ks = 0; ks < 4; ++ks) {
            short8 xa[4], pb[2];
            #pragma unroll
            for (int ti = 0; ti < 4; ++ti)
                xa[ti] = *(const short8*)&sXV[(wi * 64 + ti * 16 + m16) * 128
                                              + (((ks * 4 + quad) ^ m16) * 8)];
            #pragma unroll
            for (int tj = 0; tj < 2; ++tj)
                pb[tj] = *(const short8*)&sP[(wj * 32 + tj * 16 + m16) * 128
                                             + (((ks * 4 + quad) ^ m16) * 8)];
            #pragma unroll
            for (int ti = 0; ti < 4; ++ti)
                #pragma unroll
                for (int tj = 0; tj < 2; ++tj)
                    acc[ti][tj] = __builtin_amdgcn_mfma_f32_16x16x32_bf16(
                        xa[ti], pb[tj], acc[ti][tj], 0, 0, 0);
        }
        __syncthreads();   // protect sQ/sXV/sP before next chunk
    }

    // colsum reduce: quad butterfly, then cross-wi via LDS (sP reused as float buf)
    #pragma unroll
    for (int tj = 0; tj < 2; ++tj) {
        csa[tj] += __shfl_xor(csa[tj], 16);
        csa[tj] += __shfl_xor(csa[tj], 32);
    }
    float* fb = (float*)sP;
    if (lane < 16) {
        #pragma unroll
        for (int tj = 0; tj < 2; ++tj)
            fb[wi * 128 + wj * 32 + tj * 16 + lane] = csa[tj];
    }
    __syncthreads();
    float csr[2];
    #pragma unroll
    for (int tj = 0; tj < 2; ++tj) {
        const float c0 = fb[0   + wj * 32 + tj * 16 + m16];
        const float c1 = fb[128 + wj * 32 + tj * 16 + m16];
        csr[tj] = 1.0f / (1e-9f + c0 + c1);
    }

    const half_t* hb = h + (size_t)b * sNC;
    half_t* db = dS + (size_t)b * sNC;
    #pragma unroll
    for (int ti = 0; ti < 4; ++ti) {
        const int cg = i0 + wi * 64 + ti * 16 + quad * 4;
        #pragma unroll
        for (int tj = 0; tj < 2; ++tj) {
            const int mg = j0 + wj * 32 + tj * 16 + m16;
            const half4 hv = *(const half4*)&hb[(size_t)mg * Cc + cg];
            half4 o;
            #pragma unroll
            for (int r = 0; r < 4; ++r)
                o[r] = (half_t)((float)hv[r] - acc[ti][tj][r] * csr[tj]);
            *(half4*)&db[(size_t)mg * Cc + cg] = o;
        }
    }
}

// x [B,C,N] fp32 -> xT [B,N,C] fp16
__global__ __launch_bounds__(256)
void xpose_cast(const float* __restrict__ x, half_t* __restrict__ xT)
{
    __shared__ half_t tile[32][33];
    const int tx = threadIdx.x & 31, ty = threadIdx.x >> 5;
    const int n0 = blockIdx.x * 32, c0 = blockIdx.y * 32, b = blockIdx.z;
    #pragma unroll
    for (int r = 0; r < 4; ++r)
        tile[ty * 4 + r][tx] =
            (half_t)x[((size_t)b * Cc + c0 + ty * 4 + r) * Nn + n0 + tx];
    __syncthreads();
    #pragma unroll
    for (int r = 0; r < 4; ++r)
        xT[((size_t)b * Nn + n0 + ty * 4 + r) * Cc + c0 + tx] = tile[tx][ty * 4 + r];
}

// single kernel casting all 5 weight tensors into one fp16 arena
__global__ __launch_bounds__(256)
void castall(const float* __restrict__ c1, const float* __restrict__ c2,
             const float* __restrict__ qk, const float* __restrict__ vw,
             const float* __restrict__ tw, half_t* __restrict__ dst)
{
    const int i = (blockIdx.x * 256 + threadIdx.x) * 4;   // grid 768 -> 786432 elems
    const float* s; int o;
    if      (i < 65536)  { s = c1; o = 0; }
    else if (i < 131072) { s = c2; o = 65536; }
    else if (i < 196608) { s = qk; o = 131072; }
    else if (i < 458752) { s = vw; o = 196608; }
    else                 { s = tw; o = 458752; }
    const float4v v = *(const float4v*)(s + (i - o));
    half4 out;
    #pragma unroll
    for (int r = 0; r < 4; ++r) out[r] = (half_t)v[r];
    *(half4*)(dst + i) = out;
}

extern "C" void kernel_launch(void* const* d_in, const int* in_sizes, int n_in,
                              void* d_out, int out_size, void* d_ws, size_t ws_size,
                              hipStream_t stream)
{
    const float* x    = (const float*)d_in[0];
    const float* c1w  = (const float*)d_in[1];
    const float* c2w  = (const float*)d_in[2];
    const float* bn1g = (const float*)d_in[3], *bn1b = (const float*)d_in[4];
    const float* bn1m = (const float*)d_in[5], *bn1v = (const float*)d_in[6];
    const float* bn2g = (const float*)d_in[7], *bn2b = (const float*)d_in[8];
    const float* bn2m = (const float*)d_in[9], *bn2v = (const float*)d_in[10];
    const float* qkw  = (const float*)d_in[11];
    const float* vw   = (const float*)d_in[12];
    const float* vb   = (const float*)d_in[13];
    const float* tw   = (const float*)d_in[14];
    const float* tb   = (const float*)d_in[15];
    const float* sag  = (const float*)d_in[16];
    const float* sab  = (const float*)d_in[17];
    const float* sam  = (const float*)d_in[18];
    const float* sav  = (const float*)d_in[19];
    float* out = (float*)d_out;

    // ---- workspace layout ----
    char* ws = (char*)d_ws;
    const size_t HSZ = (size_t)Bn * Nn * Cc * 2;          // 16 MB
    half_t* xT   = (half_t*)(ws);
    half_t* hA   = (half_t*)(ws + HSZ);
    half_t* hBuf = (half_t*)(ws + 2 * HSZ);
    half_t* q_s  = (half_t*)(ws + 3 * HSZ);               // 4 MB
    half_t* xv_s = (half_t*)(ws + 3 * HSZ + (size_t)4194304);       // 16 MB (bf16)
    half_t* d_s  = (half_t*)(ws + 4 * HSZ + (size_t)4194304);       // 16 MB
    float*  offp = (float*) (ws + 5 * HSZ + (size_t)4194304);       // 128 KB
    float*  Pbuf = (float*) (ws + 5 * HSZ + (size_t)4325376);       // 4 MB
    half_t* warena = (half_t*)(ws + 5 * HSZ + (size_t)8519680);     // 1.5 MB
    half_t* wc1  = warena;
    half_t* wc2  = wc1 + 65536;
    half_t* wqk  = wc2 + 65536;
    half_t* wv   = wqk + 65536;
    half_t* wt   = wv  + 262144;

    dim3 blk(256);

    castall<<<768, blk, 0, stream>>>(c1w, c2w, qkw, vw, tw, warena);
    xpose_cast<<<dim3(Nn / 32, Cc / 32, Bn), blk, 0, stream>>>(x, xT);

    // conv1 / conv2 -> h[n][c] fp16
    mgemm<EPI_H, 128, 128, 2, 2, false><<<dim3(16, 2, Bn), blk, 0, stream>>>(
        wc1, 0, xT, sNC, hA, sNC, Cc, nullptr, 0, nullptr, 0,
        nullptr, bn1g, bn1b, bn1m, bn1v, Cc);
    mgemm<EPI_H, 128, 128, 2, 2, false><<<dim3(16, 2, Bn), blk, 0, stream>>>(
        wc2, 0, hA, sNC, hBuf, sNC, Cc, nullptr, 0, nullptr, 0,
        nullptr, bn2g, bn2b, bn2m, bn2v, Cc);

    half_t* hcur = hBuf;
    half_t* hnxt = hA;
    for (int L = 0; L < 4; ++L) {
        // q[n][64] fp16
        mgemm<EPI_RAW, 64, 256, 1, 4, false><<<dim3(8, 1, Bn), blk, 0, stream>>>(
            wqk + (long)L * C4 * Cc, 0, hcur, sNC, q_s, sNQ, C4,
            nullptr, 0, nullptr, 0,
            nullptr, nullptr, nullptr, nullptr, nullptr, Cc);
        // softmax stats (no E materialization)
        estats<<<dim3(16, 16, Bn), blk, 0, stream>>>(q_s, Pbuf);
        statsreduce<<<128, blk, 0, stream>>>(Pbuf, offp);
        // xv[c][n] bf16
        mgemm<EPI_XV, 128, 128, 2, 2, true><<<dim3(2, 16, Bn), blk, 0, stream>>>(
            hcur, sNC, wv + (long)L * Cc * Cc, 0, xv_s, (long)Cc * Nn, Nn,
            nullptr, 0, nullptr, 0,
            vb + L * Cc, nullptr, nullptr, nullptr, nullptr, Cc);
        // fused: d[m][c] = h - (xv@attn)/(1e-9+colsum)
        flashxr<<<dim3(16, 2, Bn), dim3(512), 0, stream>>>(
            q_s, xv_s, hcur, offp, d_s);
        // out_L = h + relu(bn(tw @ d + tb)); h_next fp16
        mgemm<EPI_T, 128, 128, 2, 2, false><<<dim3(2, 16, Bn), blk, 0, stream>>>(
            d_s, sNC, wt + (long)L * Cc * Cc, 0,
            out + (long)L * Cc * Nn, (long)4 * Cc * Nn, Nn,
            hcur, sNC, (L < 3) ? hnxt : nullptr, sNC,
            tb + L * Cc, sag + L * Cc, sab + L * Cc, sam + L * Cc, sav + L * Cc,
            Cc);
        half_t* tmp = hcur; hcur = hnxt; hnxt = tmp;
    }
}